// Round 1
// baseline (308.256 us; speedup 1.0000x reference)
//
#include <hip/hip_runtime.h>
#include <hip/hip_cooperative_groups.h>
#include <math.h>

namespace cg = cooperative_groups;

#define EPSF 1e-5f

// B=256, C=3, H=W=64 (HW=4096), G=128
// ws layout (float offsets)
constexpr int OFF_RED1 = 0;        // 192*2  bn1 partials (sum,sumsq)
constexpr int OFF_A1B1 = 384;      // 6      folded bn1 affine (fallback path only)
constexpr int OFF_RED2 = 512;      // 256*9  t-moment partials
constexpr int OFF_W2E  = 4096;     // 128*128*9 effective conv2 weights
constexpr int OFF_M    = OFF_W2E + 128 * 128 * 9;  // 256*128 pooled conv2 output

__device__ __forceinline__ float wave_sum(float v) {
    #pragma unroll
    for (int off = 32; off > 0; off >>= 1) v += __shfl_down(v, off);
    return v;
}

struct KParams {
    const float *agent, *world, *action;
    const float *bn1_g, *bn1_b, *conv1w, *bn2_g, *bn2_b, *conv2w, *bn3_g, *bn3_b;
    const float *fc1w, *fc1b, *lnmig, *lnmib, *miw1, *miw2;
    const float *embc, *embe, *embnc, *embns, *embp;
    const float *lncag, *lncab, *caw1, *cab1, *caw2, *cab2;
    const float *lncg, *lncb, *cw, *lndg, *lndb, *dw1, *dw2;
    float *out, *ws;
};

// ============================================================================
// Fused single-dispatch cooperative kernel: 256 blocks x 512 threads, 1 blk/CU.
// phase1 = kA (bn1 partial stats + effective conv2 weights)
// phase2 = kB + LDS staging of t = relu(bn1(x))   [t stays resident for phase3]
// phase3 = kC minus re-staging (reads LDS-resident t)
// phase4 = kE widened to 512 threads
// ============================================================================
__global__ __launch_bounds__(512, 2) void fused(KParams p) {
    cg::grid_group grid = cg::this_grid();
    const int blk = blockIdx.x, tid = threadIdx.x;
    float* red1 = p.ws + OFF_RED1;
    float* red2 = p.ws + OFF_RED2;
    float* w2e  = p.ws + OFF_W2E;
    float* m    = p.ws + OFF_M;

    __shared__ __align__(16) float T[12288];   // t planes (phase2->3), reused as scratch later
    __shared__ __align__(16) float Fsh[1152];
    __shared__ float wt[384], bt[128], momp[288], mom[9], ab[6];
    __shared__ float wred[8][9], lss[8], lss2[8], mrow[128];
    __shared__ float xsh[128], lnv[28], lnca[24], lnsc[56], h1[100], h2[100], h3[50], cat[60];

    // ---------------- phase 1: bn1 partial stats (blk<192) + w2e (blk>=192) ----------------
    if (blk < 192) {
        int c = blk % 3, seg = blk / 3;  // 64 segs x 4 b
        float s = 0.f, s2 = 0.f;
        #pragma unroll
        for (int bb = 0; bb < 4; ++bb) {
            const float4* q = (const float4*)(p.world + (size_t)((seg * 4 + bb) * 3 + c) * 4096);
            for (int i = tid; i < 1024; i += 512) {
                float4 v = q[i];
                s += (v.x + v.y) + (v.z + v.w);
                s2 = fmaf(v.x, v.x, s2); s2 = fmaf(v.y, v.y, s2);
                s2 = fmaf(v.z, v.z, s2); s2 = fmaf(v.w, v.w, s2);
            }
        }
        float a = wave_sum(s), b2_ = wave_sum(s2);
        if ((tid & 63) == 0) { lss[tid >> 6] = a; lss2[tid >> 6] = b2_; }
        __syncthreads();
        if (tid == 0) {
            float ts = 0.f, ts2 = 0.f;
            #pragma unroll
            for (int wv = 0; wv < 8; ++wv) { ts += lss[wv]; ts2 += lss2[wv]; }
            red1[blk * 2 + 0] = ts; red1[blk * 2 + 1] = ts2;
        }
    } else if (tid < 256) {
        // effective conv2 weights: feature order S,R0,R63,C0,C63,u00,u0_63,u63_0,u63_63
        int idx = (blk - 192) * 256 + tid;  // 16384 (g,g') pairs
        int g = idx >> 7, gp = idx & 127;
        const float* wp = p.conv2w + (size_t)(g * 128 + gp) * 9;
        float v0 = wp[0], v1 = wp[1], v2 = wp[2], v3 = wp[3], v4 = wp[4],
              v5 = wp[5], v6 = wp[6], v7 = wp[7], v8 = wp[8];
        float c9[9];
        c9[0] = ((v0 + v1) + (v2 + v3)) + ((v4 + v5) + (v6 + v7)) + v8;
        c9[1] = -(v6 + v7 + v8);
        c9[2] = -(v0 + v1 + v2);
        c9[3] = -(v2 + v5 + v8);
        c9[4] = -(v0 + v3 + v6);
        c9[5] = v8; c9[6] = v6; c9[7] = v2; c9[8] = v0;
        #pragma unroll
        for (int k = 0; k < 9; ++k) {
            int jj = gp * 9 + k;                                     // 0..1151
            w2e[(size_t)(jj >> 2) * 512 + g * 4 + (jj & 3)] = c9[k]; // [jblk][g][4]
        }
    }
    grid.sync();

    // ---------------- phase 2: bn1 finalize (in-block) + stage t in LDS + 3x3 moments ------
    const int b = blk;
    if (tid < 3) {
        float s = 0.f, s2 = 0.f;
        for (int seg = 0; seg < 64; ++seg) {
            s  += red1[(seg * 3 + tid) * 2 + 0];
            s2 += red1[(seg * 3 + tid) * 2 + 1];
        }
        float n = 256.f * 4096.f;
        float mean = s / n, var = s2 / n - mean * mean;
        float a = p.bn1_g[tid] * rsqrtf(var + EPSF);
        ab[tid] = a; ab[3 + tid] = p.bn1_b[tid] - mean * a;
    }
    __syncthreads();
    {
        float A0 = ab[0], A1 = ab[1], A2 = ab[2];
        float B0 = ab[3], B1 = ab[4], B2 = ab[5];
        const float4* p0 = (const float4*)(p.world + (size_t)(b * 3 + 0) * 4096);
        const float4* p1 = (const float4*)(p.world + (size_t)(b * 3 + 1) * 4096);
        const float4* p2 = (const float4*)(p.world + (size_t)(b * 3 + 2) * 4096);
        float acc[9] = {0, 0, 0, 0, 0, 0, 0, 0, 0};
        for (int i = tid; i < 1024; i += 512) {
            float4 v0 = p0[i], v1 = p1[i], v2 = p2[i];
            float4 t0, t1, t2;
            #define MOM(e) { \
                float u0 = fmaxf(0.f, fmaf(A0, v0.e, B0)); \
                float u1 = fmaxf(0.f, fmaf(A1, v1.e, B1)); \
                float u2 = fmaxf(0.f, fmaf(A2, v2.e, B2)); \
                t0.e = u0; t1.e = u1; t2.e = u2; \
                acc[0] += u0; acc[1] += u1; acc[2] += u2; \
                acc[3] = fmaf(u0, u0, acc[3]); acc[4] = fmaf(u0, u1, acc[4]); \
                acc[5] = fmaf(u0, u2, acc[5]); acc[6] = fmaf(u1, u1, acc[6]); \
                acc[7] = fmaf(u1, u2, acc[7]); acc[8] = fmaf(u2, u2, acc[8]); }
            MOM(x) MOM(y) MOM(z) MOM(w)
            #undef MOM
            *(float4*)&T[i * 4]        = t0;
            *(float4*)&T[4096 + i * 4] = t1;
            *(float4*)&T[8192 + i * 4] = t2;
        }
        #pragma unroll
        for (int k = 0; k < 9; ++k) {
            float v = wave_sum(acc[k]);
            if ((tid & 63) == 0) wred[tid >> 6][k] = v;
        }
        __syncthreads();
        if (tid < 9) {
            float s = 0.f;
            #pragma unroll
            for (int wv = 0; wv < 8; ++wv) s += wred[wv][tid];
            red2[b * 9 + tid] = s;
        }
    }
    grid.sync();

    // ---------------- phase 3: bn2 fold + conv + boundary features + contract -> m[b,:] -----
    if (tid < 288) {  // 32 segs x 9 moments, 8 rows each
        int seg = tid / 9, k = tid - seg * 9;
        float s = 0.f;
        #pragma unroll
        for (int r = 0; r < 8; ++r) s += red2[(seg * 8 + r) * 9 + k];
        momp[tid] = s;
    }
    __syncthreads();
    if (tid < 9) {
        float s = 0.f;
        #pragma unroll
        for (int sg = 0; sg < 32; ++sg) s += momp[sg * 9 + tid];
        mom[tid] = s / (256.f * 4096.f);
    }
    __syncthreads();
    if (tid < 128) {  // bn2 fold into conv1 weights
        int g = tid;
        float wa = p.conv1w[g * 3 + 0], wb = p.conv1w[g * 3 + 1], wc = p.conv1w[g * 3 + 2];
        float mean = wa * mom[0] + wb * mom[1] + wc * mom[2];
        float ey2 = wa * wa * mom[3] + wb * wb * mom[6] + wc * wc * mom[8]
                  + 2.f * (wa * wb * mom[4] + wa * wc * mom[5] + wb * wc * mom[7]);
        float var = ey2 - mean * mean;
        float a = p.bn2_g[g] * rsqrtf(var + EPSF);
        wt[g * 3 + 0] = a * wa; wt[g * 3 + 1] = a * wb; wt[g * 3 + 2] = a * wc;
        bt[g] = p.bn2_b[g] - mean * a;
    }
    __syncthreads();
    int gl = tid & 31, qc = tid >> 5;  // 16 chunks x 256 pixels; 4 g's per thread
    {
        float w0[4], w1v[4], w2v[4], bw[4], S[4] = {0, 0, 0, 0};
        #pragma unroll
        for (int j = 0; j < 4; ++j) {
            int g = gl + 32 * j;
            w0[j] = wt[g * 3 + 0]; w1v[j] = wt[g * 3 + 1];
            w2v[j] = wt[g * 3 + 2]; bw[j] = bt[g];
        }
        int base = qc * 256;
        #pragma unroll 4
        for (int i = 0; i < 64; ++i) {
            int pp = base + i * 4;
            float4 t0 = *(const float4*)&T[pp];
            float4 t1 = *(const float4*)&T[4096 + pp];
            float4 t2 = *(const float4*)&T[8192 + pp];
            #pragma unroll
            for (int j = 0; j < 4; ++j) {
                float u0 = fmaxf(0.f, fmaf(w0[j], t0.x, fmaf(w1v[j], t1.x, fmaf(w2v[j], t2.x, bw[j]))));
                float u1 = fmaxf(0.f, fmaf(w0[j], t0.y, fmaf(w1v[j], t1.y, fmaf(w2v[j], t2.y, bw[j]))));
                float u2 = fmaxf(0.f, fmaf(w0[j], t0.z, fmaf(w1v[j], t1.z, fmaf(w2v[j], t2.z, bw[j]))));
                float u3 = fmaxf(0.f, fmaf(w0[j], t0.w, fmaf(w1v[j], t1.w, fmaf(w2v[j], t2.w, bw[j]))));
                S[j] += (u0 + u1) + (u2 + u3);
            }
        }
        // boundary post-pass: 128 g x 4 tasks, one thread each
        {
            int g = tid & 127, task = tid >> 7;
            float vw0 = wt[g * 3 + 0], vw1 = wt[g * 3 + 1], vw2 = wt[g * 3 + 2], vb = bt[g];
            float s = 0.f, first = 0.f, last = 0.f;
            int p0 = (task == 1) ? 63 * 64 : ((task == 3) ? 63 : 0);
            int stp = (task >= 2) ? 64 : 1;
            #pragma unroll 4
            for (int i = 0; i < 64; ++i) {
                int pp = p0 + i * stp;
                float u = fmaxf(0.f, fmaf(vw0, T[pp], fmaf(vw1, T[4096 + pp], fmaf(vw2, T[8192 + pp], vb))));
                s += u;
                if (i == 0) first = u;
                if (i == 63) last = u;
            }
            Fsh[g * 9 + 1 + task] = s;          // R0,R63,C0,C63
            if (task == 0) { Fsh[g * 9 + 5] = first; Fsh[g * 9 + 6] = last; }   // u00, u0_63
            if (task == 1) { Fsh[g * 9 + 7] = first; Fsh[g * 9 + 8] = last; }   // u63_0, u63_63
        }
        __syncthreads();  // everyone done reading t planes
        #pragma unroll
        for (int j = 0; j < 4; ++j) T[(gl + 32 * j) * 17 + qc] = S[j];
    }
    __syncthreads();
    if (tid < 128) {
        float s = 0.f;
        #pragma unroll
        for (int qq = 0; qq < 16; ++qq) s += T[tid * 17 + qq];
        Fsh[tid * 9 + 0] = s;
    }
    __syncthreads();
    {
        int chunk = tid >> 7, g = tid & 127;
        float acc = 0.f;
        #pragma unroll 4
        for (int t = 0; t < 72; ++t) {
            int jb = chunk * 72 + t;
            float4 wv = *(const float4*)&w2e[(size_t)jb * 512 + g * 4];
            float4 fv = *(const float4*)&Fsh[jb * 4];
            acc = fmaf(wv.x, fv.x, fmaf(wv.y, fv.y, fmaf(wv.z, fv.z, fmaf(wv.w, fv.w, acc))));
        }
        __syncthreads();
        T[chunk * 128 + g] = acc;
    }
    __syncthreads();
    if (tid < 128) {
        float v = (T[tid] + T[128 + tid] + T[256 + tid] + T[384 + tid]) * (1.f / 4096.f);
        m[b * 128 + tid] = v;
        mrow[tid] = v;
    }
    grid.sync();

    // ---------------- phase 4: bn3 (redundant batch stats, L2-hot m) + all heads ------------
    {
        int g = tid & 127, qtr = tid >> 7;   // 4 quarters x 64 rows
        float s = 0.f, s2 = 0.f;
        for (int i = 0; i < 64; ++i) {
            float v = m[(qtr * 64 + i) * 128 + g];
            s += v; s2 = fmaf(v, v, s2);
        }
        T[tid] = s; T[512 + tid] = s2;
    }
    __syncthreads();
    if (tid < 128) {
        float s  = T[tid] + T[128 + tid] + T[256 + tid] + T[384 + tid];
        float s2 = T[512 + tid] + T[640 + tid] + T[768 + tid] + T[896 + tid];
        float mean = s / 256.f, var = s2 / 256.f - mean * mean;
        float a = p.bn3_g[tid] * rsqrtf(var + EPSF);
        float bb = p.bn3_b[tid] - mean * a;
        xsh[tid] = fmaxf(0.f, fmaf(a, mrow[tid], bb));
    }
    // three LayerNorms, one per wave
    int l = tid & 63, w = tid >> 6;
    if (w == 0) {  // agent LN(28)
        float av = (l < 28) ? p.agent[b * 28 + l] : 0.f;
        float s = wave_sum(av), s2 = wave_sum(av * av);
        s = __shfl(s, 0); s2 = __shfl(s2, 0);
        float mean = s / 28.f, var = s2 / 28.f - mean * mean;
        float rs = rsqrtf(var + EPSF);
        if (l < 28) lnv[l] = (av - mean) * rs * p.lnmig[l] + p.lnmib[l];
    } else if (w == 1) {  // actions build + LN(24)
        const float* ap = p.action + b * 15;
        float actv = 0.f;
        if (l < 24) {
            if (l < 4)       actv = ap[l];
            else if (l < 7)  { int ix = (int)ap[4];  actv = p.embc[ix * 3 + (l - 4)]; }
            else if (l < 10) { int ix = (int)ap[5];  actv = p.embe[ix * 3 + (l - 7)]; }
            else if (l < 13) actv = ap[l - 4];
            else if (l < 16) { int ix = (int)ap[9];  actv = p.embnc[ix * 3 + (l - 13)]; }
            else if (l < 18) { int ix = (int)ap[10]; actv = p.embns[ix * 2 + (l - 16)]; }
            else if (l < 21) { int ix = (int)ap[11]; actv = p.embp[ix * 3 + (l - 18)]; }
            else             actv = ap[l - 9];
        }
        float s = wave_sum(actv), s2 = wave_sum(actv * actv);
        s = __shfl(s, 0); s2 = __shfl(s2, 0);
        float mean = s / 24.f, var = s2 / 24.f - mean * mean;
        float rs = rsqrtf(var + EPSF);
        if (l < 24) lnca[l] = (actv - mean) * rs * p.lncag[l] + p.lncab[l];
    } else if (w == 2) {  // dist LN(56): sc = [zeros(28), agent]
        float g1v = (l < 56) ? p.agent[b * 28 + (l < 28 ? l : l - 28)] : 0.f;
        float av = (l < 28) ? g1v : 0.f;
        float s = wave_sum(av), s2 = wave_sum(av * av);
        s = __shfl(s, 0); s2 = __shfl(s2, 0);
        float mean = s / 56.f, var = s2 / 56.f - mean * mean;
        float rs = rsqrtf(var + EPSF);
        if (l < 56) {
            float vv = (l < 28) ? 0.f : g1v;
            lnsc[l] = (vv - mean) * rs * p.lndg[l] + p.lndb[l];
        }
    }
    __syncthreads();
    // first-layer neurons, thread-parallel
    if (tid < 100) {
        float a = 0.f;
        for (int i = 0; i < 28; ++i) a = fmaf(p.miw1[tid * 28 + i], lnv[i], a);
        h1[tid] = fmaxf(0.f, a);
    } else if (tid < 200) {
        int j = tid - 100;
        float a = p.cab1[j];
        for (int i = 0; i < 24; ++i) a = fmaf(p.caw1[j * 24 + i], lnca[i], a);
        h2[j] = fmaxf(0.f, a);
    } else if (tid < 250) {
        int j = tid - 200;
        float a = 0.f;
        for (int i = 0; i < 56; ++i) a = fmaf(p.dw1[j * 56 + i], lnsc[i], a);
        h3[j] = tanhf(a);
    }
    __syncthreads();
    // second layers + dist output
    if (tid < 20) {
        float a = 0.f;
        for (int i = 0; i < 100; ++i) a = fmaf(p.miw2[tid * 100 + i], h1[i], a);
        cat[20 + tid] = fmaxf(0.f, a);
    } else if (tid >= 64 && tid < 84) {
        int j = tid - 64;
        float a = p.cab2[j];
        for (int i = 0; i < 100; ++i) a = fmaf(p.caw2[j * 100 + i], h2[i], a);
        cat[40 + j] = fmaxf(0.f, a);
    } else if (tid >= 128 && tid < 148) {
        int j = tid - 128;
        float a = p.fc1b[j];
        for (int i = 0; i < 128; ++i) a = fmaf(p.fc1w[j * 128 + i], xsh[i], a);
        cat[j] = fmaxf(0.f, a);
    } else if (tid >= 192 && tid < 256) {
        int l3 = tid - 192;
        float dt = (l3 < 50) ? p.dw2[l3] * h3[l3] : 0.f;
        dt = wave_sum(dt);
        if (l3 == 0) p.out[256 + b] = tanhf(dt);
    }
    __syncthreads();
    // combined head LN(60) -> dot -> tanh (wave 0)
    if (w == 0) {
        float cv = (l < 60) ? cat[l] : 0.f;
        float ss = wave_sum(cv), ss2 = wave_sum(cv * cv);
        ss = __shfl(ss, 0); ss2 = __shfl(ss2, 0);
        float mean60 = ss / 60.f, var60 = ss2 / 60.f - mean60 * mean60;
        float rs60 = rsqrtf(var60 + EPSF);
        float term = (l < 60) ? p.cw[l] * ((cv - mean60) * rs60 * p.lncg[l] + p.lncb[l]) : 0.f;
        term = wave_sum(term);
        if (l == 0) p.out[b] = tanhf(term);
    }
}

// ============================================================================
// Fallback: proven 4-kernel path (verbatim from the 186 µs baseline), used only
// if the cooperative launch is rejected by the runtime/capture.
// ============================================================================
__global__ __launch_bounds__(256) void kA(const float* __restrict__ x,
                                          const float* __restrict__ w2,
                                          float* __restrict__ red1,
                                          float* __restrict__ w2e) {
    int blk = blockIdx.x, tid = threadIdx.x;
    if (blk < 192) {
        int c = blk % 3, seg = blk / 3;
        float s = 0.f, s2 = 0.f;
        for (int bb = 0; bb < 4; ++bb) {
            int b = seg * 4 + bb;
            const float4* p = (const float4*)(x + (size_t)(b * 3 + c) * 4096);
            for (int i = tid; i < 1024; i += 256) {
                float4 v = p[i];
                s += v.x + v.y + v.z + v.w;
                s2 = fmaf(v.x, v.x, s2); s2 = fmaf(v.y, v.y, s2);
                s2 = fmaf(v.z, v.z, s2); s2 = fmaf(v.w, v.w, s2);
            }
        }
        __shared__ float ls[4], ls2[4];
        float ws_ = wave_sum(s), ws2_ = wave_sum(s2);
        if ((tid & 63) == 0) { ls[tid >> 6] = ws_; ls2[tid >> 6] = ws2_; }
        __syncthreads();
        if (tid == 0) {
            red1[blk * 2 + 0] = ls[0] + ls[1] + ls[2] + ls[3];
            red1[blk * 2 + 1] = ls2[0] + ls2[1] + ls2[2] + ls2[3];
        }
    } else {
        int idx = (blk - 192) * 256 + tid;
        int g = idx >> 7, gp = idx & 127;
        const float* wp = w2 + (size_t)(g * 128 + gp) * 9;
        float v0 = wp[0], v1 = wp[1], v2 = wp[2], v3 = wp[3], v4 = wp[4],
              v5 = wp[5], v6 = wp[6], v7 = wp[7], v8 = wp[8];
        float c[9];
        c[0] = ((v0 + v1) + (v2 + v3)) + ((v4 + v5) + (v6 + v7)) + v8;
        c[1] = -(v6 + v7 + v8);
        c[2] = -(v0 + v1 + v2);
        c[3] = -(v2 + v5 + v8);
        c[4] = -(v0 + v3 + v6);
        c[5] = v8; c[6] = v6; c[7] = v2; c[8] = v0;
        #pragma unroll
        for (int k = 0; k < 9; ++k) {
            int jj = gp * 9 + k;
            w2e[(size_t)(jj >> 2) * 512 + g * 4 + (jj & 3)] = c[k];
        }
    }
}

__global__ __launch_bounds__(256) void kB(const float* __restrict__ x,
                                          const float* __restrict__ red1,
                                          const float* __restrict__ g1,
                                          const float* __restrict__ b1,
                                          float* __restrict__ red2,
                                          float* __restrict__ a1b1) {
    __shared__ float ab[6];
    int b = blockIdx.x, tid = threadIdx.x;
    if (tid < 3) {
        float s = 0.f, s2 = 0.f;
        for (int seg = 0; seg < 64; ++seg) {
            s  += red1[(seg * 3 + tid) * 2 + 0];
            s2 += red1[(seg * 3 + tid) * 2 + 1];
        }
        float n = 256.f * 4096.f;
        float mean = s / n, var = s2 / n - mean * mean;
        float a = g1[tid] * rsqrtf(var + EPSF);
        ab[tid] = a; ab[3 + tid] = b1[tid] - mean * a;
        if (b == 0) { a1b1[tid] = a; a1b1[3 + tid] = ab[3 + tid]; }
    }
    __syncthreads();
    float A0 = ab[0], A1 = ab[1], A2 = ab[2];
    float B0 = ab[3], B1 = ab[4], B2 = ab[5];
    float acc[9] = {0, 0, 0, 0, 0, 0, 0, 0, 0};
    const float4* p0 = (const float4*)(x + (size_t)(b * 3 + 0) * 4096);
    const float4* p1 = (const float4*)(x + (size_t)(b * 3 + 1) * 4096);
    const float4* p2 = (const float4*)(x + (size_t)(b * 3 + 2) * 4096);
    for (int i = tid; i < 1024; i += 256) {
        float4 v0 = p0[i], v1 = p1[i], v2 = p2[i];
        #define MOM(e) { \
            float t0 = fmaxf(0.f, fmaf(A0, v0.e, B0)); \
            float t1 = fmaxf(0.f, fmaf(A1, v1.e, B1)); \
            float t2 = fmaxf(0.f, fmaf(A2, v2.e, B2)); \
            acc[0] += t0; acc[1] += t1; acc[2] += t2; \
            acc[3] = fmaf(t0, t0, acc[3]); acc[4] = fmaf(t0, t1, acc[4]); \
            acc[5] = fmaf(t0, t2, acc[5]); acc[6] = fmaf(t1, t1, acc[6]); \
            acc[7] = fmaf(t1, t2, acc[7]); acc[8] = fmaf(t2, t2, acc[8]); }
        MOM(x) MOM(y) MOM(z) MOM(w)
        #undef MOM
    }
    __shared__ float lw[4][9];
    #pragma unroll
    for (int k = 0; k < 9; ++k) {
        float v = wave_sum(acc[k]);
        if ((tid & 63) == 0) lw[tid >> 6][k] = v;
    }
    __syncthreads();
    if (tid == 0) {
        #pragma unroll
        for (int k = 0; k < 9; ++k)
            red2[b * 9 + k] = lw[0][k] + lw[1][k] + lw[2][k] + lw[3][k];
    }
}

__global__ __launch_bounds__(512) void kC(const float* __restrict__ x,
                                          const float* __restrict__ red2,
                                          const float* __restrict__ w1,
                                          const float* __restrict__ g2,
                                          const float* __restrict__ b2,
                                          const float* __restrict__ a1b1,
                                          const float* __restrict__ w2e,
                                          float* __restrict__ m) {
    __shared__ __align__(16) float lds[12288];
    __shared__ __align__(16) float Fsh[1152];
    __shared__ float wt[384], bt[128], momp[288], mom[9], ab[6];
    int b = blockIdx.x, tid = threadIdx.x;
    if (tid < 6) ab[tid] = a1b1[tid];
    if (tid < 288) {
        int seg = tid / 9, k = tid - seg * 9;
        float s = 0.f;
        #pragma unroll
        for (int r = 0; r < 8; ++r) s += red2[(seg * 8 + r) * 9 + k];
        momp[tid] = s;
    }
    __syncthreads();
    if (tid < 9) {
        float s = 0.f;
        #pragma unroll
        for (int sg = 0; sg < 32; ++sg) s += momp[sg * 9 + tid];
        mom[tid] = s / (256.f * 4096.f);
    }
    {
        float A0 = ab[0], A1 = ab[1], A2 = ab[2];
        float B0 = ab[3], B1 = ab[4], B2 = ab[5];
        const float4* xb = (const float4*)(x + (size_t)b * 3 * 4096);
        for (int i = tid; i < 3072; i += 512) {
            float4 v = xb[i];
            int c = i >> 10;
            float a = (c == 0) ? A0 : ((c == 1) ? A1 : A2);
            float bb = (c == 0) ? B0 : ((c == 1) ? B1 : B2);
            v.x = fmaxf(0.f, fmaf(a, v.x, bb));
            v.y = fmaxf(0.f, fmaf(a, v.y, bb));
            v.z = fmaxf(0.f, fmaf(a, v.z, bb));
            v.w = fmaxf(0.f, fmaf(a, v.w, bb));
            *(float4*)&lds[i << 2] = v;
        }
    }
    __syncthreads();
    if (tid < 128) {
        int g = tid;
        float wa = w1[g * 3 + 0], wb = w1[g * 3 + 1], wc = w1[g * 3 + 2];
        float mean = wa * mom[0] + wb * mom[1] + wc * mom[2];
        float ey2 = wa * wa * mom[3] + wb * wb * mom[6] + wc * wc * mom[8]
                  + 2.f * (wa * wb * mom[4] + wa * wc * mom[5] + wb * wc * mom[7]);
        float var = ey2 - mean * mean;
        float a = g2[g] * rsqrtf(var + EPSF);
        wt[g * 3 + 0] = a * wa; wt[g * 3 + 1] = a * wb; wt[g * 3 + 2] = a * wc;
        bt[g] = b2[g] - mean * a;
    }
    __syncthreads();
    int gl = tid & 31, q = tid >> 5;
    {
        float w0[4], w1v[4], w2v[4], bw[4], S[4] = {0, 0, 0, 0};
        #pragma unroll
        for (int j = 0; j < 4; ++j) {
            int g = gl + 32 * j;
            w0[j] = wt[g * 3 + 0]; w1v[j] = wt[g * 3 + 1];
            w2v[j] = wt[g * 3 + 2]; bw[j] = bt[g];
        }
        int base = q * 256;
        #pragma unroll 4
        for (int i = 0; i < 64; ++i) {
            int pp = base + i * 4;
            float4 t0 = *(const float4*)&lds[pp];
            float4 t1 = *(const float4*)&lds[4096 + pp];
            float4 t2 = *(const float4*)&lds[8192 + pp];
            #pragma unroll
            for (int j = 0; j < 4; ++j) {
                float u0 = fmaxf(0.f, fmaf(w0[j], t0.x, fmaf(w1v[j], t1.x, fmaf(w2v[j], t2.x, bw[j]))));
                float u1 = fmaxf(0.f, fmaf(w0[j], t0.y, fmaf(w1v[j], t1.y, fmaf(w2v[j], t2.y, bw[j]))));
                float u2 = fmaxf(0.f, fmaf(w0[j], t0.z, fmaf(w1v[j], t1.z, fmaf(w2v[j], t2.z, bw[j]))));
                float u3 = fmaxf(0.f, fmaf(w0[j], t0.w, fmaf(w1v[j], t1.w, fmaf(w2v[j], t2.w, bw[j]))));
                S[j] += (u0 + u1) + (u2 + u3);
            }
        }
        {
            int g = tid & 127, task = tid >> 7;
            float vw0 = wt[g * 3 + 0], vw1 = wt[g * 3 + 1], vw2 = wt[g * 3 + 2], vb = bt[g];
            float s = 0.f, first = 0.f, last = 0.f;
            int p0 = (task == 1) ? 63 * 64 : ((task == 3) ? 63 : 0);
            int stp = (task >= 2) ? 64 : 1;
            #pragma unroll 4
            for (int i = 0; i < 64; ++i) {
                int p = p0 + i * stp;
                float u = fmaxf(0.f, fmaf(vw0, lds[p], fmaf(vw1, lds[4096 + p], fmaf(vw2, lds[8192 + p], vb))));
                s += u;
                if (i == 0) first = u;
                if (i == 63) last = u;
            }
            Fsh[g * 9 + 1 + task] = s;
            if (task == 0) { Fsh[g * 9 + 5] = first; Fsh[g * 9 + 6] = last; }
            if (task == 1) { Fsh[g * 9 + 7] = first; Fsh[g * 9 + 8] = last; }
        }
        __syncthreads();
        #pragma unroll
        for (int j = 0; j < 4; ++j) lds[(gl + 32 * j) * 17 + q] = S[j];
    }
    __syncthreads();
    if (tid < 128) {
        float s = 0.f;
        #pragma unroll
        for (int qq = 0; qq < 16; ++qq) s += lds[tid * 17 + qq];
        Fsh[tid * 9 + 0] = s;
    }
    __syncthreads();
    {
        int chunk = tid >> 7, g = tid & 127;
        float acc = 0.f;
        #pragma unroll 4
        for (int t = 0; t < 72; ++t) {
            int jb = chunk * 72 + t;
            float4 wv = *(const float4*)&w2e[(size_t)jb * 512 + g * 4];
            float4 fv = *(const float4*)&Fsh[jb * 4];
            acc = fmaf(wv.x, fv.x, fmaf(wv.y, fv.y, fmaf(wv.z, fv.z, fmaf(wv.w, fv.w, acc))));
        }
        __syncthreads();
        lds[chunk * 128 + g] = acc;
    }
    __syncthreads();
    if (tid < 128)
        m[b * 128 + tid] = (lds[tid] + lds[128 + tid] + lds[256 + tid] + lds[384 + tid]) * (1.f / 4096.f);
}

__global__ __launch_bounds__(256) void kE(
    const float* __restrict__ m, const float* __restrict__ g3, const float* __restrict__ b3,
    const float* __restrict__ agent, const float* __restrict__ action,
    const float* __restrict__ fc1w, const float* __restrict__ fc1b,
    const float* __restrict__ lnmig, const float* __restrict__ lnmib,
    const float* __restrict__ miw1, const float* __restrict__ miw2,
    const float* __restrict__ embc, const float* __restrict__ embe,
    const float* __restrict__ embnc, const float* __restrict__ embns,
    const float* __restrict__ embp,
    const float* __restrict__ lncag, const float* __restrict__ lncab,
    const float* __restrict__ caw1, const float* __restrict__ cab1,
    const float* __restrict__ caw2, const float* __restrict__ cab2,
    const float* __restrict__ lncg, const float* __restrict__ lncb,
    const float* __restrict__ cw,
    const float* __restrict__ lndg, const float* __restrict__ lndb,
    const float* __restrict__ dw1, const float* __restrict__ dw2,
    float* __restrict__ out) {
    __shared__ float red[4][128];
    __shared__ float xsh[128];
    __shared__ float lnv[28], lnca[24], lnsc[56], h1[100], h2[100], h3[50], cat[60];
    int b = blockIdx.x, tid = threadIdx.x;
    {
        int g = tid & 127, half = tid >> 7;
        float s = 0.f, s2 = 0.f;
        for (int i = 0; i < 128; ++i) {
            float v = m[(half * 128 + i) * 128 + g];
            s += v; s2 = fmaf(v, v, s2);
        }
        red[half * 2 + 0][g] = s;
        red[half * 2 + 1][g] = s2;
    }
    __syncthreads();
    if (tid < 128) {
        float s = red[0][tid] + red[2][tid], s2 = red[1][tid] + red[3][tid];
        float mean = s / 256.f, var = s2 / 256.f - mean * mean;
        float a = g3[tid] * rsqrtf(var + EPSF);
        float bb = b3[tid] - mean * a;
        xsh[tid] = fmaxf(0.f, fmaf(a, m[b * 128 + tid], bb));
    }
    int l = tid & 63, w = tid >> 6;
    if (w == 0) {
        float av = (l < 28) ? agent[b * 28 + l] : 0.f;
        float s = wave_sum(av), s2 = wave_sum(av * av);
        s = __shfl(s, 0); s2 = __shfl(s2, 0);
        float mean = s / 28.f, var = s2 / 28.f - mean * mean;
        float rs = rsqrtf(var + EPSF);
        if (l < 28) lnv[l] = (av - mean) * rs * lnmig[l] + lnmib[l];
    } else if (w == 1) {
        const float* ab = action + b * 15;
        float actv = 0.f;
        if (l < 24) {
            if (l < 4)       actv = ab[l];
            else if (l < 7)  { int ix = (int)ab[4];  actv = embc[ix * 3 + (l - 4)]; }
            else if (l < 10) { int ix = (int)ab[5];  actv = embe[ix * 3 + (l - 7)]; }
            else if (l < 13) actv = ab[l - 4];
            else if (l < 16) { int ix = (int)ab[9];  actv = embnc[ix * 3 + (l - 13)]; }
            else if (l < 18) { int ix = (int)ab[10]; actv = embns[ix * 2 + (l - 16)]; }
            else if (l < 21) { int ix = (int)ab[11]; actv = embp[ix * 3 + (l - 18)]; }
            else             actv = ab[l - 9];
        }
        float s = wave_sum(actv), s2 = wave_sum(actv * actv);
        s = __shfl(s, 0); s2 = __shfl(s2, 0);
        float mean = s / 24.f, var = s2 / 24.f - mean * mean;
        float rs = rsqrtf(var + EPSF);
        if (l < 24) lnca[l] = (actv - mean) * rs * lncag[l] + lncab[l];
    } else if (w == 2) {
        float g1v = (l < 56) ? agent[b * 28 + (l < 28 ? l : l - 28)] : 0.f;
        float av = (l < 28) ? g1v : 0.f;
        float s = wave_sum(av), s2 = wave_sum(av * av);
        s = __shfl(s, 0); s2 = __shfl(s2, 0);
        float mean = s / 56.f, var = s2 / 56.f - mean * mean;
        float rs = rsqrtf(var + EPSF);
        if (l < 56) {
            float vv = (l < 28) ? 0.f : g1v;
            lnsc[l] = (vv - mean) * rs * lndg[l] + lndb[l];
        }
    }
    __syncthreads();
    if (tid < 100) {
        float a = 0.f;
        for (int i = 0; i < 28; ++i) a = fmaf(miw1[tid * 28 + i], lnv[i], a);
        h1[tid] = fmaxf(0.f, a);
    } else if (tid < 200) {
        int j = tid - 100;
        float a = cab1[j];
        for (int i = 0; i < 24; ++i) a = fmaf(caw1[j * 24 + i], lnca[i], a);
        h2[j] = fmaxf(0.f, a);
    } else if (tid < 250) {
        int j = tid - 200;
        float a = 0.f;
        for (int i = 0; i < 56; ++i) a = fmaf(dw1[j * 56 + i], lnsc[i], a);
        h3[j] = tanhf(a);
    }
    __syncthreads();
    if (tid < 20) {
        float a = 0.f;
        for (int i = 0; i < 100; ++i) a = fmaf(miw2[tid * 100 + i], h1[i], a);
        cat[20 + tid] = fmaxf(0.f, a);
    } else if (tid >= 64 && tid < 84) {
        int j = tid - 64;
        float a = cab2[j];
        for (int i = 0; i < 100; ++i) a = fmaf(caw2[j * 100 + i], h2[i], a);
        cat[40 + j] = fmaxf(0.f, a);
    } else if (tid >= 128 && tid < 148) {
        int j = tid - 128;
        float a = fc1b[j];
        for (int i = 0; i < 128; ++i) a = fmaf(fc1w[j * 128 + i], xsh[i], a);
        cat[j] = fmaxf(0.f, a);
    } else if (tid >= 192) {
        int l3 = tid - 192;
        float dt = (l3 < 50) ? dw2[l3] * h3[l3] : 0.f;
        dt = wave_sum(dt);
        if (l3 == 0) out[256 + b] = tanhf(dt);
    }
    __syncthreads();
    if (w == 0) {
        float cv = (l < 60) ? cat[l] : 0.f;
        float ss = wave_sum(cv), ss2 = wave_sum(cv * cv);
        ss = __shfl(ss, 0); ss2 = __shfl(ss2, 0);
        float mean60 = ss / 60.f, var60 = ss2 / 60.f - mean60 * mean60;
        float rs60 = rsqrtf(var60 + EPSF);
        float term = (l < 60) ? cw[l] * ((cv - mean60) * rs60 * lncg[l] + lncb[l]) : 0.f;
        term = wave_sum(term);
        if (l == 0) out[b] = tanhf(term);
    }
}

extern "C" void kernel_launch(void* const* d_in, const int* in_sizes, int n_in,
                              void* d_out, int out_size, void* d_ws, size_t ws_size,
                              hipStream_t stream) {
    (void)in_sizes; (void)n_in; (void)out_size; (void)ws_size;
    KParams hp;
    hp.agent  = (const float*)d_in[0];
    hp.world  = (const float*)d_in[1];
    hp.action = (const float*)d_in[2];
    hp.bn1_g  = (const float*)d_in[3];
    hp.bn1_b  = (const float*)d_in[4];
    hp.conv1w = (const float*)d_in[5];
    hp.bn2_g  = (const float*)d_in[6];
    hp.bn2_b  = (const float*)d_in[7];
    hp.conv2w = (const float*)d_in[8];
    hp.bn3_g  = (const float*)d_in[9];
    hp.bn3_b  = (const float*)d_in[10];
    hp.fc1w   = (const float*)d_in[11];
    hp.fc1b   = (const float*)d_in[12];
    hp.lnmig  = (const float*)d_in[13];
    hp.lnmib  = (const float*)d_in[14];
    hp.miw1   = (const float*)d_in[15];
    hp.miw2   = (const float*)d_in[16];
    hp.embc   = (const float*)d_in[17];
    hp.embe   = (const float*)d_in[18];
    hp.embnc  = (const float*)d_in[19];
    hp.embns  = (const float*)d_in[20];
    hp.embp   = (const float*)d_in[21];
    hp.lncag  = (const float*)d_in[22];
    hp.lncab  = (const float*)d_in[23];
    hp.caw1   = (const float*)d_in[24];
    hp.cab1   = (const float*)d_in[25];
    hp.caw2   = (const float*)d_in[26];
    hp.cab2   = (const float*)d_in[27];
    hp.lncg   = (const float*)d_in[28];
    hp.lncb   = (const float*)d_in[29];
    hp.cw     = (const float*)d_in[30];
    hp.lndg   = (const float*)d_in[31];
    hp.lndb   = (const float*)d_in[32];
    hp.dw1    = (const float*)d_in[33];
    hp.dw2    = (const float*)d_in[34];
    hp.out = (float*)d_out;
    hp.ws  = (float*)d_ws;

    void* args[] = {&hp};
    hipError_t err = hipLaunchCooperativeKernel((const void*)fused, dim3(256), dim3(512),
                                                args, 0, stream);
    if (err != hipSuccess) {
        // fallback: proven 4-kernel path (baseline ~186 µs)
        float* ws = hp.ws;
        hipLaunchKernelGGL(kA, dim3(256), dim3(256), 0, stream,
                           hp.world, hp.conv2w, ws + OFF_RED1, ws + OFF_W2E);
        hipLaunchKernelGGL(kB, dim3(256), dim3(256), 0, stream,
                           hp.world, ws + OFF_RED1, hp.bn1_g, hp.bn1_b, ws + OFF_RED2, ws + OFF_A1B1);
        hipLaunchKernelGGL(kC, dim3(256), dim3(512), 0, stream,
                           hp.world, ws + OFF_RED2, hp.conv1w, hp.bn2_g, hp.bn2_b, ws + OFF_A1B1,
                           ws + OFF_W2E, ws + OFF_M);
        hipLaunchKernelGGL(kE, dim3(256), dim3(256), 0, stream,
                           ws + OFF_M, hp.bn3_g, hp.bn3_b, hp.agent, hp.action, hp.fc1w, hp.fc1b,
                           hp.lnmig, hp.lnmib, hp.miw1, hp.miw2,
                           hp.embc, hp.embe, hp.embnc, hp.embns, hp.embp,
                           hp.lncag, hp.lncab, hp.caw1, hp.cab1, hp.caw2, hp.cab2,
                           hp.lncg, hp.lncb, hp.cw, hp.lndg, hp.lndb, hp.dw1, hp.dw2, hp.out);
    }
}

// Round 2
// 175.284 us; speedup vs baseline: 1.7586x; 1.7586x over previous
//
#include <hip/hip_runtime.h>
#include <math.h>

#define EPSF 1e-5f

// B=256, C=3, H=W=64 (HW=4096), G=128
// ws layout (float offsets)
constexpr int OFF_RED1 = 0;        // 256*6  per-b bn1 partials (s,s2 per channel)
constexpr int OFF_A1B1 = 1536;     // 6      folded bn1 affine a[3],b[3] (written by kB blk0)
constexpr int OFF_RED2 = 2048;     // 256*9  t-moment partials
constexpr int OFF_W2E  = 8192;     // 128*128*9 effective conv2 weights
constexpr int OFF_M    = OFF_W2E + 128 * 128 * 9;  // 256*128 pooled conv2 output

__device__ __forceinline__ float wave_sum(float v) {
    #pragma unroll
    for (int off = 32; off > 0; off >>= 1) v += __shfl_down(v, off);
    return v;
}

// ---------- kA: per-b bn1 partial stats + effective conv2 weights ----------
// 256 blocks x 512 threads: block b reads its 3 contiguous planes (48 KB),
// 8 waves/CU for HBM latency hiding; plus 64 w2e (g,g') pairs per block.
__global__ __launch_bounds__(512) void kA(const float* __restrict__ x,
                                          const float* __restrict__ w2,
                                          float* __restrict__ red1,
                                          float* __restrict__ w2e) {
    int b = blockIdx.x, tid = threadIdx.x;
    const float4* p0 = (const float4*)(x + (size_t)(b * 3 + 0) * 4096);
    const float4* p1 = (const float4*)(x + (size_t)(b * 3 + 1) * 4096);
    const float4* p2 = (const float4*)(x + (size_t)(b * 3 + 2) * 4096);
    float s0 = 0.f, s1 = 0.f, s2c = 0.f, q0 = 0.f, q1 = 0.f, q2 = 0.f;
    for (int i = tid; i < 1024; i += 512) {
        float4 v0 = p0[i], v1 = p1[i], v2 = p2[i];
        s0 += (v0.x + v0.y) + (v0.z + v0.w);
        q0 = fmaf(v0.x, v0.x, q0); q0 = fmaf(v0.y, v0.y, q0);
        q0 = fmaf(v0.z, v0.z, q0); q0 = fmaf(v0.w, v0.w, q0);
        s1 += (v1.x + v1.y) + (v1.z + v1.w);
        q1 = fmaf(v1.x, v1.x, q1); q1 = fmaf(v1.y, v1.y, q1);
        q1 = fmaf(v1.z, v1.z, q1); q1 = fmaf(v1.w, v1.w, q1);
        s2c += (v2.x + v2.y) + (v2.z + v2.w);
        q2 = fmaf(v2.x, v2.x, q2); q2 = fmaf(v2.y, v2.y, q2);
        q2 = fmaf(v2.z, v2.z, q2); q2 = fmaf(v2.w, v2.w, q2);
    }
    __shared__ float lw[8][6];
    {
        float a0 = wave_sum(s0), b0 = wave_sum(q0);
        float a1 = wave_sum(s1), b1 = wave_sum(q1);
        float a2 = wave_sum(s2c), b2 = wave_sum(q2);
        if ((tid & 63) == 0) {
            int w = tid >> 6;
            lw[w][0] = a0; lw[w][1] = b0;
            lw[w][2] = a1; lw[w][3] = b1;
            lw[w][4] = a2; lw[w][5] = b2;
        }
    }
    __syncthreads();
    if (tid < 6) {
        float t = 0.f;
        #pragma unroll
        for (int w = 0; w < 8; ++w) t += lw[w][tid];
        red1[b * 6 + tid] = t;
    }
    // effective conv2 weights: 64 pairs per block
    // feature order S,R0,R63,C0,C63,u00,u0_63,u63_0,u63_63
    if (tid < 64) {
        int idx = b * 64 + tid;  // 16384 (g,g') pairs
        int g = idx >> 7, gp = idx & 127;
        const float* wp = w2 + (size_t)(g * 128 + gp) * 9;  // [ky][kx]
        float v0 = wp[0], v1 = wp[1], v2 = wp[2], v3 = wp[3], v4 = wp[4],
              v5 = wp[5], v6 = wp[6], v7 = wp[7], v8 = wp[8];
        float c[9];
        c[0] = ((v0 + v1) + (v2 + v3)) + ((v4 + v5) + (v6 + v7)) + v8;
        c[1] = -(v6 + v7 + v8);
        c[2] = -(v0 + v1 + v2);
        c[3] = -(v2 + v5 + v8);
        c[4] = -(v0 + v3 + v6);
        c[5] = v8; c[6] = v6; c[7] = v2; c[8] = v0;
        #pragma unroll
        for (int k = 0; k < 9; ++k) {
            int jj = gp * 9 + k;                                     // 0..1151
            w2e[(size_t)(jj >> 2) * 512 + g * 4 + (jj & 3)] = c[k];  // [jblk][g][4]
        }
    }
}

// ---------- kB: bn1 finalize (3 waves, lane-parallel) + per-b 3x3 moments of t ----------
__global__ __launch_bounds__(512) void kB(const float* __restrict__ x,
                                          const float* __restrict__ red1,
                                          const float* __restrict__ g1,
                                          const float* __restrict__ b1,
                                          float* __restrict__ red2,
                                          float* __restrict__ a1b1) {
    __shared__ float ab[6];
    int b = blockIdx.x, tid = threadIdx.x;
    if (tid < 192) {  // wave w = channel c; lanes parallel over b
        int c = tid >> 6, q = tid & 63;
        float s = 0.f, s2 = 0.f;
        #pragma unroll
        for (int k = 0; k < 4; ++k) {
            int bb = q + 64 * k;
            s  += red1[bb * 6 + c * 2 + 0];
            s2 += red1[bb * 6 + c * 2 + 1];
        }
        s = wave_sum(s); s2 = wave_sum(s2);
        if (q == 0) {
            float n = 256.f * 4096.f;
            float mean = s / n, var = s2 / n - mean * mean;
            float a = g1[c] * rsqrtf(var + EPSF);
            ab[c] = a; ab[3 + c] = b1[c] - mean * a;
            if (b == 0) { a1b1[c] = a; a1b1[3 + c] = b1[c] - mean * a; }
        }
    }
    __syncthreads();
    float A0 = ab[0], A1 = ab[1], A2 = ab[2];
    float B0 = ab[3], B1 = ab[4], B2 = ab[5];
    float acc[9] = {0, 0, 0, 0, 0, 0, 0, 0, 0};
    const float4* p0 = (const float4*)(x + (size_t)(b * 3 + 0) * 4096);
    const float4* p1 = (const float4*)(x + (size_t)(b * 3 + 1) * 4096);
    const float4* p2 = (const float4*)(x + (size_t)(b * 3 + 2) * 4096);
    for (int i = tid; i < 1024; i += 512) {
        float4 v0 = p0[i], v1 = p1[i], v2 = p2[i];
        #define MOM(e) { \
            float t0 = fmaxf(0.f, fmaf(A0, v0.e, B0)); \
            float t1 = fmaxf(0.f, fmaf(A1, v1.e, B1)); \
            float t2 = fmaxf(0.f, fmaf(A2, v2.e, B2)); \
            acc[0] += t0; acc[1] += t1; acc[2] += t2; \
            acc[3] = fmaf(t0, t0, acc[3]); acc[4] = fmaf(t0, t1, acc[4]); \
            acc[5] = fmaf(t0, t2, acc[5]); acc[6] = fmaf(t1, t1, acc[6]); \
            acc[7] = fmaf(t1, t2, acc[7]); acc[8] = fmaf(t2, t2, acc[8]); }
        MOM(x) MOM(y) MOM(z) MOM(w)
        #undef MOM
    }
    __shared__ float lw[8][9];
    #pragma unroll
    for (int k = 0; k < 9; ++k) {
        float v = wave_sum(acc[k]);
        if ((tid & 63) == 0) lw[tid >> 6][k] = v;
    }
    __syncthreads();
    if (tid < 9) {
        float s = 0.f;
        #pragma unroll
        for (int w = 0; w < 8; ++w) s += lw[w][tid];
        red2[b * 9 + tid] = s;
    }
}

// ---------- kC: bn2 fold + boundary features + contract -> m[b,:] ----------
// Hot loop computes ONLY the full-plane sum S (no conditionals). Row/col/corner
// features are a tiny post-pass (1 thread per (g,task), 64 u's each).
__global__ __launch_bounds__(512) void kC(const float* __restrict__ x,
                                          const float* __restrict__ red2,
                                          const float* __restrict__ w1,
                                          const float* __restrict__ g2,
                                          const float* __restrict__ b2,
                                          const float* __restrict__ a1b1,
                                          const float* __restrict__ w2e,
                                          float* __restrict__ m) {
    __shared__ __align__(16) float lds[12288];  // t planes; reused for S-reduce + contract partials
    __shared__ __align__(16) float Fsh[1152];
    __shared__ float wt[384], bt[128], momp[288], mom[9], ab[6];
    int b = blockIdx.x, tid = threadIdx.x;
    if (tid < 6) ab[tid] = a1b1[tid];
    if (tid < 288) {  // 32 segs x 9 moments, 8 rows each — independent loads
        int seg = tid / 9, k = tid - seg * 9;
        float s = 0.f;
        #pragma unroll
        for (int r = 0; r < 8; ++r) s += red2[(seg * 8 + r) * 9 + k];
        momp[tid] = s;
    }
    __syncthreads();
    if (tid < 9) {
        float s = 0.f;
        #pragma unroll
        for (int sg = 0; sg < 32; ++sg) s += momp[sg * 9 + tid];
        mom[tid] = s / (256.f * 4096.f);
    }
    // stage t planes (ab ready — barrier above)
    {
        float A0 = ab[0], A1 = ab[1], A2 = ab[2];
        float B0 = ab[3], B1 = ab[4], B2 = ab[5];
        const float4* xb = (const float4*)(x + (size_t)b * 3 * 4096);
        for (int i = tid; i < 3072; i += 512) {
            float4 v = xb[i];
            int c = i >> 10;
            float a = (c == 0) ? A0 : ((c == 1) ? A1 : A2);
            float bb = (c == 0) ? B0 : ((c == 1) ? B1 : B2);
            v.x = fmaxf(0.f, fmaf(a, v.x, bb));
            v.y = fmaxf(0.f, fmaf(a, v.y, bb));
            v.z = fmaxf(0.f, fmaf(a, v.z, bb));
            v.w = fmaxf(0.f, fmaf(a, v.w, bb));
            *(float4*)&lds[i << 2] = v;
        }
    }
    __syncthreads();
    if (tid < 128) {  // bn2 fold into conv1 weights
        int g = tid;
        float wa = w1[g * 3 + 0], wb = w1[g * 3 + 1], wc = w1[g * 3 + 2];
        float mean = wa * mom[0] + wb * mom[1] + wc * mom[2];
        float ey2 = wa * wa * mom[3] + wb * wb * mom[6] + wc * wc * mom[8]
                  + 2.f * (wa * wb * mom[4] + wa * wc * mom[5] + wb * wc * mom[7]);
        float var = ey2 - mean * mean;
        float a = g2[g] * rsqrtf(var + EPSF);
        wt[g * 3 + 0] = a * wa; wt[g * 3 + 1] = a * wb; wt[g * 3 + 2] = a * wc;
        bt[g] = b2[g] - mean * a;
    }
    __syncthreads();
    // ---- hot loop: full-plane S only ----
    int gl = tid & 31, q = tid >> 5;  // 16 chunks x 256 pixels; 4 g's per thread
    {
        float w0[4], w1v[4], w2v[4], bw[4], S[4] = {0, 0, 0, 0};
        #pragma unroll
        for (int j = 0; j < 4; ++j) {
            int g = gl + 32 * j;
            w0[j] = wt[g * 3 + 0]; w1v[j] = wt[g * 3 + 1];
            w2v[j] = wt[g * 3 + 2]; bw[j] = bt[g];
        }
        int base = q * 256;
        #pragma unroll 4
        for (int i = 0; i < 64; ++i) {
            int pp = base + i * 4;
            float4 t0 = *(const float4*)&lds[pp];
            float4 t1 = *(const float4*)&lds[4096 + pp];
            float4 t2 = *(const float4*)&lds[8192 + pp];
            #pragma unroll
            for (int j = 0; j < 4; ++j) {
                float u0 = fmaxf(0.f, fmaf(w0[j], t0.x, fmaf(w1v[j], t1.x, fmaf(w2v[j], t2.x, bw[j]))));
                float u1 = fmaxf(0.f, fmaf(w0[j], t0.y, fmaf(w1v[j], t1.y, fmaf(w2v[j], t2.y, bw[j]))));
                float u2 = fmaxf(0.f, fmaf(w0[j], t0.z, fmaf(w1v[j], t1.z, fmaf(w2v[j], t2.z, bw[j]))));
                float u3 = fmaxf(0.f, fmaf(w0[j], t0.w, fmaf(w1v[j], t1.w, fmaf(w2v[j], t2.w, bw[j]))));
                S[j] += (u0 + u1) + (u2 + u3);
            }
        }
        // ---- boundary post-pass: 128 g x 4 tasks, one thread each ----
        {
            int g = tid & 127, task = tid >> 7;
            float vw0 = wt[g * 3 + 0], vw1 = wt[g * 3 + 1], vw2 = wt[g * 3 + 2], vb = bt[g];
            float s = 0.f, first = 0.f, last = 0.f;
            int p0 = (task == 1) ? 63 * 64 : ((task == 3) ? 63 : 0);
            int stp = (task >= 2) ? 64 : 1;
            #pragma unroll 4
            for (int i = 0; i < 64; ++i) {
                int p = p0 + i * stp;
                float u = fmaxf(0.f, fmaf(vw0, lds[p], fmaf(vw1, lds[4096 + p], fmaf(vw2, lds[8192 + p], vb))));
                s += u;
                if (i == 0) first = u;
                if (i == 63) last = u;
            }
            Fsh[g * 9 + 1 + task] = s;          // R0,R63,C0,C63
            if (task == 0) { Fsh[g * 9 + 5] = first; Fsh[g * 9 + 6] = last; }   // u00, u0_63
            if (task == 1) { Fsh[g * 9 + 7] = first; Fsh[g * 9 + 8] = last; }   // u63_0, u63_63
        }
        __syncthreads();  // everyone done reading t planes
        // S-reduce across the 16 q-chunks: padded stride 17 -> conflict-free
        #pragma unroll
        for (int j = 0; j < 4; ++j) lds[(gl + 32 * j) * 17 + q] = S[j];
    }
    __syncthreads();
    if (tid < 128) {
        float s = 0.f;
        #pragma unroll
        for (int qq = 0; qq < 16; ++qq) s += lds[tid * 17 + qq];
        Fsh[tid * 9 + 0] = s;
    }
    __syncthreads();
    // contract: m[b,g] = (1/4096) * sum_j w2e[j][g] * Fsh[j], split over 4 j-chunks
    {
        int chunk = tid >> 7, g = tid & 127;
        float acc = 0.f;
        #pragma unroll 4
        for (int t = 0; t < 72; ++t) {
            int jb = chunk * 72 + t;
            float4 wv = *(const float4*)&w2e[(size_t)jb * 512 + g * 4];
            float4 fv = *(const float4*)&Fsh[jb * 4];
            acc = fmaf(wv.x, fv.x, fmaf(wv.y, fv.y, fmaf(wv.z, fv.z, fmaf(wv.w, fv.w, acc))));
        }
        __syncthreads();
        lds[chunk * 128 + g] = acc;
    }
    __syncthreads();
    if (tid < 128)
        m[b * 128 + tid] = (lds[tid] + lds[128 + tid] + lds[256 + tid] + lds[384 + tid]) * (1.f / 4096.f);
}

// ---------- kE: bn3 (redundant per-block batch stats, 512 thr) + all heads ----------
__global__ __launch_bounds__(512) void kE(
    const float* __restrict__ m, const float* __restrict__ g3, const float* __restrict__ b3,
    const float* __restrict__ agent, const float* __restrict__ action,
    const float* __restrict__ fc1w, const float* __restrict__ fc1b,
    const float* __restrict__ lnmig, const float* __restrict__ lnmib,
    const float* __restrict__ miw1, const float* __restrict__ miw2,
    const float* __restrict__ embc, const float* __restrict__ embe,
    const float* __restrict__ embnc, const float* __restrict__ embns,
    const float* __restrict__ embp,
    const float* __restrict__ lncag, const float* __restrict__ lncab,
    const float* __restrict__ caw1, const float* __restrict__ cab1,
    const float* __restrict__ caw2, const float* __restrict__ cab2,
    const float* __restrict__ lncg, const float* __restrict__ lncb,
    const float* __restrict__ cw,
    const float* __restrict__ lndg, const float* __restrict__ lndb,
    const float* __restrict__ dw1, const float* __restrict__ dw2,
    float* __restrict__ out) {
    __shared__ float sc1[512], sc2[512];
    __shared__ float xsh[128], lnv[28], lnca[24], lnsc[56], h1[100], h2[100], h3[50], cat[60];
    int b = blockIdx.x, tid = threadIdx.x;
    // bn3 batch stats (each block redundantly; m is 128KB, L2-hot)
    {
        int g = tid & 127, qtr = tid >> 7;   // 4 quarters x 64 rows
        float s = 0.f, s2 = 0.f;
        for (int i = 0; i < 64; ++i) {
            float v = m[(qtr * 64 + i) * 128 + g];
            s += v; s2 = fmaf(v, v, s2);
        }
        sc1[tid] = s; sc2[tid] = s2;
    }
    __syncthreads();
    if (tid < 128) {
        float s  = sc1[tid] + sc1[128 + tid] + sc1[256 + tid] + sc1[384 + tid];
        float s2 = sc2[tid] + sc2[128 + tid] + sc2[256 + tid] + sc2[384 + tid];
        float mean = s / 256.f, var = s2 / 256.f - mean * mean;
        float a = g3[tid] * rsqrtf(var + EPSF);
        float bb = b3[tid] - mean * a;
        xsh[tid] = fmaxf(0.f, fmaf(a, m[b * 128 + tid], bb));
    }
    // phase B: three LayerNorms, one per wave
    int l = tid & 63, w = tid >> 6;
    if (w == 0) {  // agent LN(28)
        float av = (l < 28) ? agent[b * 28 + l] : 0.f;
        float s = wave_sum(av), s2 = wave_sum(av * av);
        s = __shfl(s, 0); s2 = __shfl(s2, 0);
        float mean = s / 28.f, var = s2 / 28.f - mean * mean;
        float rs = rsqrtf(var + EPSF);
        if (l < 28) lnv[l] = (av - mean) * rs * lnmig[l] + lnmib[l];
    } else if (w == 1) {  // actions build + LN(24)
        const float* ap = action + b * 15;
        float actv = 0.f;
        if (l < 24) {
            if (l < 4)       actv = ap[l];
            else if (l < 7)  { int ix = (int)ap[4];  actv = embc[ix * 3 + (l - 4)]; }
            else if (l < 10) { int ix = (int)ap[5];  actv = embe[ix * 3 + (l - 7)]; }
            else if (l < 13) actv = ap[l - 4];
            else if (l < 16) { int ix = (int)ap[9];  actv = embnc[ix * 3 + (l - 13)]; }
            else if (l < 18) { int ix = (int)ap[10]; actv = embns[ix * 2 + (l - 16)]; }
            else if (l < 21) { int ix = (int)ap[11]; actv = embp[ix * 3 + (l - 18)]; }
            else             actv = ap[l - 9];
        }
        float s = wave_sum(actv), s2 = wave_sum(actv * actv);
        s = __shfl(s, 0); s2 = __shfl(s2, 0);
        float mean = s / 24.f, var = s2 / 24.f - mean * mean;
        float rs = rsqrtf(var + EPSF);
        if (l < 24) lnca[l] = (actv - mean) * rs * lncag[l] + lncab[l];
    } else if (w == 2) {  // dist LN(56): sc = [zeros(28), agent]
        float g1v = (l < 56) ? agent[b * 28 + (l < 28 ? l : l - 28)] : 0.f;
        float av = (l < 28) ? g1v : 0.f;
        float s = wave_sum(av), s2 = wave_sum(av * av);
        s = __shfl(s, 0); s2 = __shfl(s2, 0);
        float mean = s / 56.f, var = s2 / 56.f - mean * mean;
        float rs = rsqrtf(var + EPSF);
        if (l < 56) {
            float vv = (l < 28) ? 0.f : g1v;
            lnsc[l] = (vv - mean) * rs * lndg[l] + lndb[l];
        }
    }
    __syncthreads();
    // phase C: first-layer neurons, thread-parallel
    if (tid < 100) {
        float a = 0.f;
        for (int i = 0; i < 28; ++i) a = fmaf(miw1[tid * 28 + i], lnv[i], a);
        h1[tid] = fmaxf(0.f, a);
    } else if (tid < 200) {
        int j = tid - 100;
        float a = cab1[j];
        for (int i = 0; i < 24; ++i) a = fmaf(caw1[j * 24 + i], lnca[i], a);
        h2[j] = fmaxf(0.f, a);
    } else if (tid < 250) {
        int j = tid - 200;
        float a = 0.f;
        for (int i = 0; i < 56; ++i) a = fmaf(dw1[j * 56 + i], lnsc[i], a);
        h3[j] = tanhf(a);
    }
    __syncthreads();
    // phase D: second layers + dist output
    if (tid < 20) {
        float a = 0.f;
        for (int i = 0; i < 100; ++i) a = fmaf(miw2[tid * 100 + i], h1[i], a);
        cat[20 + tid] = fmaxf(0.f, a);
    } else if (tid >= 64 && tid < 84) {
        int j = tid - 64;
        float a = cab2[j];
        for (int i = 0; i < 100; ++i) a = fmaf(caw2[j * 100 + i], h2[i], a);
        cat[40 + j] = fmaxf(0.f, a);
    } else if (tid >= 128 && tid < 148) {
        int j = tid - 128;
        float a = fc1b[j];
        for (int i = 0; i < 128; ++i) a = fmaf(fc1w[j * 128 + i], xsh[i], a);
        cat[j] = fmaxf(0.f, a);
    } else if (tid >= 192 && tid < 256) {
        int l3 = tid - 192;
        float dt = (l3 < 50) ? dw2[l3] * h3[l3] : 0.f;
        dt = wave_sum(dt);
        if (l3 == 0) out[256 + b] = tanhf(dt);
    }
    __syncthreads();
    // phase E: combined head LN(60) -> dot -> tanh (wave 0)
    if (w == 0) {
        float cv = (l < 60) ? cat[l] : 0.f;
        float ss = wave_sum(cv), ss2 = wave_sum(cv * cv);
        ss = __shfl(ss, 0); ss2 = __shfl(ss2, 0);
        float mean60 = ss / 60.f, var60 = ss2 / 60.f - mean60 * mean60;
        float rs60 = rsqrtf(var60 + EPSF);
        float term = (l < 60) ? cw[l] * ((cv - mean60) * rs60 * lncg[l] + lncb[l]) : 0.f;
        term = wave_sum(term);
        if (l == 0) out[b] = tanhf(term);
    }
}

extern "C" void kernel_launch(void* const* d_in, const int* in_sizes, int n_in,
                              void* d_out, int out_size, void* d_ws, size_t ws_size,
                              hipStream_t stream) {
    (void)in_sizes; (void)n_in; (void)out_size; (void)ws_size;
    const float* agent  = (const float*)d_in[0];
    const float* world  = (const float*)d_in[1];
    const float* action = (const float*)d_in[2];
    const float* bn1_g  = (const float*)d_in[3];
    const float* bn1_b  = (const float*)d_in[4];
    const float* conv1w = (const float*)d_in[5];
    const float* bn2_g  = (const float*)d_in[6];
    const float* bn2_b  = (const float*)d_in[7];
    const float* conv2w = (const float*)d_in[8];
    const float* bn3_g  = (const float*)d_in[9];
    const float* bn3_b  = (const float*)d_in[10];
    const float* fc1w   = (const float*)d_in[11];
    const float* fc1b   = (const float*)d_in[12];
    const float* lnmig  = (const float*)d_in[13];
    const float* lnmib  = (const float*)d_in[14];
    const float* miw1   = (const float*)d_in[15];
    const float* miw2   = (const float*)d_in[16];
    const float* embc   = (const float*)d_in[17];
    const float* embe   = (const float*)d_in[18];
    const float* embnc  = (const float*)d_in[19];
    const float* embns  = (const float*)d_in[20];
    const float* embp   = (const float*)d_in[21];
    const float* lncag  = (const float*)d_in[22];
    const float* lncab  = (const float*)d_in[23];
    const float* caw1   = (const float*)d_in[24];
    const float* cab1   = (const float*)d_in[25];
    const float* caw2   = (const float*)d_in[26];
    const float* cab2   = (const float*)d_in[27];
    const float* lncg   = (const float*)d_in[28];
    const float* lncb   = (const float*)d_in[29];
    const float* cw     = (const float*)d_in[30];
    const float* lndg   = (const float*)d_in[31];
    const float* lndb   = (const float*)d_in[32];
    const float* dw1    = (const float*)d_in[33];
    const float* dw2    = (const float*)d_in[34];
    float* out = (float*)d_out;
    float* ws = (float*)d_ws;

    hipLaunchKernelGGL(kA, dim3(256), dim3(512), 0, stream,
                       world, conv2w, ws + OFF_RED1, ws + OFF_W2E);
    hipLaunchKernelGGL(kB, dim3(256), dim3(512), 0, stream,
                       world, ws + OFF_RED1, bn1_g, bn1_b, ws + OFF_RED2, ws + OFF_A1B1);
    hipLaunchKernelGGL(kC, dim3(256), dim3(512), 0, stream,
                       world, ws + OFF_RED2, conv1w, bn2_g, bn2_b, ws + OFF_A1B1,
                       ws + OFF_W2E, ws + OFF_M);
    hipLaunchKernelGGL(kE, dim3(256), dim3(512), 0, stream,
                       ws + OFF_M, bn3_g, bn3_b, agent, action, fc1w, fc1b,
                       lnmig, lnmib, miw1, miw2,
                       embc, embe, embnc, embns, embp,
                       lncag, lncab, caw1, cab1, caw2, cab2,
                       lncg, lncb, cw, lndg, lndb, dw1, dw2, out);
}